// Round 5
// baseline (146.264 us; speedup 1.0000x reference)
//
#include <hip/hip_runtime.h>
#include <hip/hip_bf16.h>
#include <stdint.h>

// Fastfood 2D conv, MI355X. fp32 I/O:
// input (16,256,32,32), B/G/S (1,4096), bias (512), P (4096) i32 -> out (16,512,32,32).
// Per pixel: patch j=kk*256+ch (2304, pad 4096), *B, FWHT4096, perm P, *G, FWHT4096,
// *S[0:512]+bias.
//
// R4: pixel QUADS (ow = p, p+8, p+16, p+24), 4 px per uint2 LDS slot (b64 exchanges).
// R5: fp16-native pipeline (h2 regs, v_pk_add_f16 butterflies, bitcast exchanges).
// R6: WAR-barrier elimination (own-partition write-backs); f16 ws staging.
// R7: TRUNCATED SECOND FWHT + per-thread output ownership.
//     Only oc<512 of the 4096 pass-1 outputs are kept. FWHT axis-rounds commute,
//     so pass 1 runs C(stride1) -> B(stride16) -> A(stride256, TRUNCATED): in
//     A-layout thread t holds the full stride-256 group for m=t in registers, and
//     oc=t / oc=256+t are just the sum / alternating sum (60 packed adds vs 128).
//     The per-quad epilogue redistribution (2 barriers + 36 LDS ops) vanishes:
//     outputs are born per-thread. Perm gather re-pointed to C-layout (j=16t+r).
//     Pass-0 top WAR barrier also removed (prev quad's last reads = own A-slots).
//     Barriers/quad: 9 -> 6. ws is oc-major [oc][8 x uint2]; finish kernel is an
//     LDS-free streamer (lane t owns rows oc=t,256+t).

typedef _Float16 h2 __attribute__((ext_vector_type(2)));

__device__ __forceinline__ float bf2f(uint16_t u) {
    union { uint32_t i; float f; } c; c.i = ((uint32_t)u) << 16; return c.f;
}
__device__ __forceinline__ uint16_t f2bf(float f) {  // RNE
    uint32_t u = __float_as_uint(f);
    return (uint16_t)((u + 0x7FFFu + ((u >> 16) & 1u)) >> 16);
}
__device__ __forceinline__ int swz(int j) {
    return j ^ ((j >> 5) & 7) ^ (((j >> 8) & 1) * 24) ^ (((j >> 9) & 1) * 8);
}
__device__ __forceinline__ uint32_t h2u(h2 v) {
    union { h2 h; uint32_t u; } c; c.h = v; return c.u;
}
__device__ __forceinline__ h2 u2h(uint32_t x) {
    union { h2 h; uint32_t u; } c; c.u = x; return c.h;
}
__device__ __forceinline__ h2 pkh(float a, float b) {
    h2 r; r.x = (_Float16)a; r.y = (_Float16)b; return r;
}
__device__ __forceinline__ void h16h(h2* x) {
    #pragma unroll
    for (int h = 1; h < 16; h <<= 1) {
        #pragma unroll
        for (int g = 0; g < 16; g += 2 * h) {
            #pragma unroll
            for (int u = g; u < g + h; ++u) {
                h2 a = x[u], b = x[u + h];
                x[u]     = a + b;   // -> v_pk_add_f16
                x[u + h] = a - b;
            }
        }
    }
}
// truncated stride-256 round: s = sum_r x[r], d = sum_r (-1)^r x[r]
__device__ __forceinline__ void trunc16(const h2* x, h2& s, h2& d) {
    h2 sp[8], sm[8];
    #pragma unroll
    for (int i = 0; i < 8; ++i) {
        sp[i] = x[2 * i] + x[2 * i + 1];
        sm[i] = x[2 * i] - x[2 * i + 1];
    }
    #pragma unroll
    for (int h = 4; h >= 1; h >>= 1) {
        #pragma unroll
        for (int i = 0; i < h; ++i) { sp[i] = sp[i] + sp[i + h]; sm[i] = sm[i] + sm[i + h]; }
    }
    s = sp[0]; d = sm[0];
}

__global__ __launch_bounds__(256, 2)
void fastfood_kernel(const float* __restrict__ in,
                     const float* __restrict__ Bm,
                     const float* __restrict__ Gm,
                     const float* __restrict__ Sm,
                     const float* __restrict__ bias,
                     const int* __restrict__ P,
                     float* __restrict__ ws,    // uint2 (4xh2) oc-major staging, !direct
                     float* __restrict__ out,   // used only when direct!=0
                     int direct)
{
    __shared__ uint16_t s_in[3 * 32 * 256];   // [ihrel][iw][ch] bf16, 48 KiB
    __shared__ uint2    buf2[4096];           // swizzled 4-pixel fp16 exchange, 32 KiB

    const int t  = threadIdx.x;
    const int t1 = t >> 4, t0 = t & 15;
    const int b  = blockIdx.x >> 5;
    const int oh = blockIdx.x & 31;

    // ---- stage input rows oh-1..oh+1 into LDS (coalesced float4)
    #pragma unroll
    for (int i = 0; i < 24; ++i) {
        const int idx   = t + i * 256;
        const int part  = idx & 7;
        const int ch    = (idx >> 3) & 255;
        const int ihrel = idx >> 11;
        const int ih    = oh - 1 + ihrel;
        float4 ld = make_float4(0.f, 0.f, 0.f, 0.f);
        if ((unsigned)ih < 32u) {
            ld = *reinterpret_cast<const float4*>(
                in + ((((size_t)b * 256 + ch) * 32 + ih) * 32 + part * 4));
        }
        const int base = ((ihrel * 32 + part * 4) << 8) | ch;
        s_in[base      ] = f2bf(ld.x);
        s_in[base + 256] = f2bf(ld.y);
        s_in[base + 512] = f2bf(ld.z);
        s_in[base + 768] = f2bf(ld.w);
    }

    // ---- constants
    float Bv[9];
    #pragma unroll
    for (int r = 0; r < 9; ++r) Bv[r] = Bm[r * 256 + t];
    // Perm gather now lands in C-layout: thread t owns j = 16t + r (contiguous).
    h2 Gh[16]; int PAv[16];
    #pragma unroll
    for (int r = 0; r < 16; ++r) {
        const float g = Gm[16 * t + r];
        Gh[r]  = pkh(g, g);
        PAv[r] = swz(P[16 * t + r]);
    }
    const float St = Sm[t],      Ct = bias[t];        // used in direct mode only
    const float Sd = Sm[256 + t], Cd = bias[256 + t];
    __syncthreads();

    for (int p = 0; p < 8; ++p) {             // pixel quad (ow = p, p+8, p+16, p+24)
        h2 x0[16], x1[16];                    // x0=(p, p+16), x1=(p+8, p+24)
        #pragma unroll
        for (int r = 0; r < 9; ++r) {
            const int kh = r / 3, kw = r % 3;
            const int iw = p - 1 + kw;        // iw in [-1, 9]
            float v0 = 0.f, v3 = 0.f;
            if ((unsigned)iw < 32u)        v0 = bf2f(s_in[((kh * 32 + iw     ) << 8) | t]);
            const float v1                    = bf2f(s_in[((kh * 32 + iw +  8) << 8) | t]);
            const float v2                    = bf2f(s_in[((kh * 32 + iw + 16) << 8) | t]);
            if ((unsigned)(iw + 24) < 32u) v3 = bf2f(s_in[((kh * 32 + iw + 24) << 8) | t]);
            x0[r] = pkh(v0 * Bv[r], v2 * Bv[r]);
            x1[r] = pkh(v1 * Bv[r], v3 * Bv[r]);
        }
        #pragma unroll
        for (int r = 9; r < 16; ++r) {
            x0[r] = pkh(0.f, 0.f);
            x1[r] = pkh(0.f, 0.f);
        }

        // ===== pass 0: A(str256) -> B(str16) -> C(str1), stage C-layout for gather
        h16h(x0); h16h(x1);                   // round A
        // NO sync: prev quad's last buf2 reads were this thread's own A-slots.
        #pragma unroll
        for (int r = 0; r < 16; ++r)
            buf2[swz(256 * r + t)] = make_uint2(h2u(x0[r]), h2u(x1[r]));
        __syncthreads();                      // RAW
        #pragma unroll
        for (int r = 0; r < 16; ++r) {
            const uint2 u = buf2[swz(256 * t1 + 16 * r + t0)];
            x0[r] = u2h(u.x); x1[r] = u2h(u.y);
        }
        h16h(x0); h16h(x1);                   // round B
        #pragma unroll                        // own slots -> no WAR sync
        for (int r = 0; r < 16; ++r)
            buf2[swz(256 * t1 + 16 * r + t0)] = make_uint2(h2u(x0[r]), h2u(x1[r]));
        __syncthreads();                      // RAW
        #pragma unroll
        for (int r = 0; r < 16; ++r) {
            const uint2 u = buf2[swz(256 * t1 + 16 * t0 + r)];
            x0[r] = u2h(u.x); x1[r] = u2h(u.y);
        }
        h16h(x0); h16h(x1);                   // round C
        #pragma unroll                        // own slots (stage for gather)
        for (int r = 0; r < 16; ++r)
            buf2[swz(256 * t1 + 16 * t0 + r)] = make_uint2(h2u(x0[r]), h2u(x1[r]));
        __syncthreads();                      // RAW before arbitrary-address gather

        // ===== permutation + G: gather INTO C-layout (thread t owns j = 16t+r)
        #pragma unroll
        for (int r = 0; r < 16; ++r) {
            const uint2 u = buf2[PAv[r]];
            x0[r] = Gh[r] * u2h(u.x);          // -> v_pk_mul_f16
            x1[r] = Gh[r] * u2h(u.y);
        }

        // ===== pass 1 (reordered): C(str1) -> B(str16) -> A(str256, truncated)
        h16h(x0); h16h(x1);                   // round C (C-layout is current layout)
        __syncthreads();                      // WAR: others' gathers read arbitrary slots
        #pragma unroll
        for (int r = 0; r < 16; ++r)
            buf2[swz(256 * t1 + 16 * t0 + r)] = make_uint2(h2u(x0[r]), h2u(x1[r]));
        __syncthreads();                      // RAW
        #pragma unroll
        for (int r = 0; r < 16; ++r) {
            const uint2 u = buf2[swz(256 * t1 + 16 * r + t0)];
            x0[r] = u2h(u.x); x1[r] = u2h(u.y);
        }
        h16h(x0); h16h(x1);                   // round B
        #pragma unroll                        // own slots -> no WAR sync
        for (int r = 0; r < 16; ++r)
            buf2[swz(256 * t1 + 16 * r + t0)] = make_uint2(h2u(x0[r]), h2u(x1[r]));
        __syncthreads();                      // RAW
        #pragma unroll
        for (int r = 0; r < 16; ++r) {        // A-layout: x[r] = j = 256r + t
            const uint2 u = buf2[swz(256 * r + t)];
            x0[r] = u2h(u.x); x1[r] = u2h(u.y);
        }
        // truncated round A: oc = t (sum), oc = 256+t (alternating sum)
        h2 s0, d0, s1, d1;
        trunc16(x0, s0, d0);                  // (ow p, p+16)
        trunc16(x1, s1, d1);                  // (ow p+8, p+24)

        if (!direct) {
            uint2* wsu = reinterpret_cast<uint2*>(ws);
            const size_t base = (size_t)(b * 32 + oh) * 4096;
            wsu[base + (size_t)t * 8 + p]          = make_uint2(h2u(s0), h2u(s1));
            wsu[base + (size_t)(256 + t) * 8 + p]  = make_uint2(h2u(d0), h2u(d1));
        } else {
            const size_t r0 = ((size_t)b * 512 + t) * 1024 + oh * 32;
            const size_t r1 = ((size_t)b * 512 + 256 + t) * 1024 + oh * 32;
            out[r0 + p]      = St * (float)s0.x + Ct;
            out[r0 + p +  8] = St * (float)s1.x + Ct;
            out[r0 + p + 16] = St * (float)s0.y + Ct;
            out[r0 + p + 24] = St * (float)s1.y + Ct;
            out[r1 + p]      = Sd * (float)d0.x + Cd;
            out[r1 + p +  8] = Sd * (float)d1.x + Cd;
            out[r1 + p + 16] = Sd * (float)d0.y + Cd;
            out[r1 + p + 24] = Sd * (float)d1.y + Cd;
        }
    }
}

// ws (b,oh)[oc][8 x uint2(h2 pixel-pairs)] -> out (b,oc,oh,ow) f32 with S*x+bias.
// R7: LDS-free streamer. Lane t owns rows oc=t and oc=256+t of its (b,oh) slab:
// reads 64B contiguous per row (lane-major 4KB wave span, fully used), unpacks,
// f32 FMA, stores the full 128B output row as 8 float4 (lines fully dirty).
__global__ __launch_bounds__(256)
void finish_kernel(const float* __restrict__ wsf,
                   const float* __restrict__ Sm,
                   const float* __restrict__ bias,
                   float* __restrict__ out)
{
    const int t  = threadIdx.x;
    const int b  = blockIdx.x >> 5;
    const int oh = blockIdx.x & 31;
    const uint2* src = reinterpret_cast<const uint2*>(wsf) + (size_t)(b * 32 + oh) * 4096;

    #pragma unroll
    for (int half = 0; half < 2; ++half) {
        const int oc = half * 256 + t;
        const float S = Sm[oc], C = bias[oc];
        const uint2* row = src + (size_t)oc * 8;
        float o[32];
        #pragma unroll
        for (int p = 0; p < 8; ++p) {
            const uint2 u = row[p];
            const h2 a = u2h(u.x), c = u2h(u.y);
            o[p]      = S * (float)a.x + C;   // ow = p
            o[p +  8] = S * (float)c.x + C;   // ow = p+8
            o[p + 16] = S * (float)a.y + C;   // ow = p+16
            o[p + 24] = S * (float)c.y + C;   // ow = p+24
        }
        float* dst = out + ((size_t)b * 512 + oc) * 1024 + oh * 32;
        #pragma unroll
        for (int g = 0; g < 8; ++g)
            *reinterpret_cast<float4*>(dst + 4 * g) =
                make_float4(o[4 * g], o[4 * g + 1], o[4 * g + 2], o[4 * g + 3]);
    }
}

extern "C" void kernel_launch(void* const* d_in, const int* in_sizes, int n_in,
                              void* d_out, int out_size, void* d_ws, size_t ws_size,
                              hipStream_t stream) {
    const float* in   = (const float*)d_in[0];
    const float* Bm   = (const float*)d_in[1];
    const float* Gm   = (const float*)d_in[2];
    const float* Sm   = (const float*)d_in[3];
    const float* bias = (const float*)d_in[4];
    const int*   P    = (const int*)d_in[5];
    float* out = (float*)d_out;
    float* ws  = (float*)d_ws;

    const size_t need = (size_t)16 * 32 * 4096 * 8;  // 16.8 MB oc-major h2 staging
    const int direct = (ws_size < need) ? 1 : 0;

    dim3 grid(16 * 32), block(256);
    fastfood_kernel<<<grid, block, 0, stream>>>(in, Bm, Gm, Sm, bias, P, ws, out, direct);
    if (!direct)
        finish_kernel<<<grid, block, 0, stream>>>(ws, Sm, bias, out);
}